// Round 2
// baseline (494.318 us; speedup 1.0000x reference)
//
#include <hip/hip_runtime.h>

// Problem constants: N=512, BS=64, DIM=256, SIZE=8192
#define T_TOTAL 32768   // N*BS queries
#define D       256
#define K       8192
#define BQ      64      // queries per block tile (2 row-tiles of 32) — shared by all 4 waves
#define KSPLIT  4
#define KSLICE  (K / KSPLIT)
#define NSLICE  (KSPLIT * 4)        // (slice, wn) pairs write disjoint partial slices
#define NCT32   (K / 32)            // 256 code-tiles of 32
#define KT_STRIDE (NCT32 * 64 * 8)  // halves per 16-dim kt slab = 131072
#define NQB     (T_TOTAL / BQ)      // 512 query-blocks

typedef _Float16 half4f   __attribute__((ext_vector_type(4)));
typedef _Float16 half8f   __attribute__((ext_vector_type(8)));
typedef float    floatx16 __attribute__((ext_vector_type(16)));

// d_out scratch: Bhi/Blo after the first PARTIAL_F floats. If ws is big enough,
// partial lives in ws (enables fused reduce+gather); else at d_out head (R12 path).
#define PARTIAL_F 1048576
#define BHALVES   2097152   // halves per B array (16 * 131072)

__device__ __forceinline__ _Float16 hi16(float x) { return (_Float16)x; }
__device__ __forceinline__ _Float16 lo16(float x, _Float16 h) { return (_Float16)(x - (float)h); }
__device__ __forceinline__ void split4(float4 v, half4f& h, half4f& l) {
    _Float16 hx = hi16(v.x), hy = hi16(v.y), hz = hi16(v.z), hw = hi16(v.w);
    h = (half4f){hx, hy, hz, hw};
    l = (half4f){lo16(v.x, hx), lo16(v.y, hy), lo16(v.z, hz), lo16(v.w, hw)};
}

// ---- kernel 1: fused vocab prep: hv2 (fp32-exact) + fp16 hi/lo 32x32x16-fragment split ----
// 256 blocks, one 32-code tile each. Wave w handles codes 8w..8w+7 (lane = k4 along D).
// Fragment order for mfma_32x32x16_f16 B: lane = col + 32*(k>>3), elem i = k&7, per 16-dim slab.
__global__ void prep_kernel(const float* __restrict__ vocab,
                            _Float16* __restrict__ bhi, _Float16* __restrict__ blo,
                            float* __restrict__ hv2) {
    const int ct = blockIdx.x;           // 32-code tile 0..255
    const int t  = threadIdx.x;
    const int k4 = t & 63;               // float4 index along D
    const int w  = t >> 6;
    const float4* voc4 = (const float4*)vocab;
    const int kt = k4 >> 2;              // 16-dim slab (4 float4 per slab)
    const int q  = k4 & 3;               // float4 within slab
    const int fl = 32 * (q >> 1);        // lane high-half from k-octet
    const int i0 = (q & 1) * 4;          // elem offset within the 8-half fragment
    float ss[8];
    #pragma unroll
    for (int ci = 0; ci < 8; ++ci) {
        int cc = w * 8 + ci;             // code within tile
        float4 v = voc4[(size_t)(ct * 32 + cc) * (D / 4) + k4];
        half4f hh, ll;
        split4(v, hh, ll);
        size_t off = (((size_t)kt * NCT32 + ct) * 64 + (cc + fl)) * 8 + i0;
        *(half4f*)&bhi[off] = hh;
        *(half4f*)&blo[off] = ll;
        ss[ci] = v.x * v.x + v.y * v.y + v.z * v.z + v.w * v.w;
    }
    #pragma unroll
    for (int ci = 0; ci < 8; ++ci) {
        float s = ss[ci];
        #pragma unroll
        for (int off = 32; off; off >>= 1) s += __shfl_down(s, off, 64);
        if ((t & 63) == 0) hv2[ct * 32 + w * 8 + ci] = 0.5f * s;
    }
}

// -------- kernel 2: MFMA argmin; 3-term split; 32x32x16; B prefetch distance 2 --------
// block 256 = 4 waves; wave wn covers a 64-code quadrant (2 nj tiles of 32); all waves
// share 64 A rows. grid 2048; XCD swizzle locks one K-slice per XCD (B slice in L2).
// R1 lesson: 16-dim stage (12 MFMA ~110cy) < L2 latency (~200cy) exposed vmcnt stalls.
// Fix: period-4 static pipeline, B at distance 2 (~240cy cover), A (LDS ~120cy) at
// distance 1. Last-stage prefetches target the NEXT c0 tile (no drain at boundaries).
// bidx packed 2x16-bit/reg (-16 VGPR) to pay for the 2 extra B sets (+32 VGPR).
__launch_bounds__(256, 2)
__global__ void argmin_kernel(const float* __restrict__ seq,
                              const _Float16* __restrict__ bhi,
                              const _Float16* __restrict__ blo,
                              const float* __restrict__ hv2,
                              float2* __restrict__ partial) {
    // A LDS in fragment order [mi 0..1][kt 0..15][flane 0..63][8], XOR-swizzled by kt<<3
    __shared__ _Float16 AhL[2 * 16 * 64 * 8];   // 32 KB
    __shared__ _Float16 AlL[2 * 16 * 64 * 8];   // 32 KB

    const int t    = threadIdx.x;
    const int lane = t & 63;
    const int wn   = t >> 6;            // code quadrant 0..3
    const int bi   = blockIdx.x;
    const int slice = (bi & 7) >> 1;    // 0..3  (XCD-locked K-slice)
    const int qb    = (bi >> 3) * 2 + (bi & 1);  // 0..511
    const int q0   = qb * BQ;
    const int k0   = slice * KSLICE;

    const float4* seq4 = (const float4*)seq;

    // ---- prologue: split A (64 rows x 256 dims) into fragment-order LDS, once ----
    #pragma unroll
    for (int i = 0; i < 16; ++i) {
        int f   = t + 256 * i;          // 0..4095 float4s
        int row = f >> 6;               // 0..63
        int d4  = f & 63;               // float4 along D
        float4 v = seq4[(size_t)(q0 + row) * (D / 4) + d4];
        half4f h, l;
        split4(v, h, l);
        int kt = d4 >> 2, qq = d4 & 3;
        int off = (((((row >> 5) * 16 + kt) * 64) + ((row & 31) + 32 * (qq >> 1))) * 8
                   + (qq & 1) * 4)
                  ^ (kt << 3);          // swizzle: write conflicts 32-way -> 4-way
        *(half4f*)&AhL[off] = h;
        *(half4f*)&AlL[off] = l;
    }
    __syncthreads();   // the ONLY barrier

    float    best[32];
    unsigned bidxp[16];                 // 2x16-bit packed indices (K fits in 13 bits)
    #pragma unroll
    for (int b = 0; b < 32; ++b) best[b] = 3.4e38f;
    #pragma unroll
    for (int b = 0; b < 16; ++b) bidxp[b] = 0u;

    const _Float16* bh_l = bhi + (size_t)lane * 8;
    const _Float16* bl_l = blo + (size_t)lane * 8;

    // B prefetch: slab id X in [0,17]; X>=16 wraps to next c0 tile's slab X-16
    // (cb advance per c0i is 8 tiles * 512 = 4096 halves). Reads stay inside the
    // bhi/blo region of d_out (worst case ~6KB past blo is still within d_out).
#define PF_B(BH, BL, X) do {                                                   \
        const size_t kb_ = (size_t)((X) & 15) * KT_STRIDE + cb                 \
                           + (size_t)((X) >> 4) * 4096;                        \
        BH[0] = *(const half8f*)&bh_l[kb_];                                    \
        BH[1] = *(const half8f*)&bh_l[kb_ + 512];                              \
        BL[0] = *(const half8f*)&bl_l[kb_];                                    \
        BL[1] = *(const half8f*)&bl_l[kb_ + 512];                              \
    } while (0)

#define PF_A(AH, AL, X) do {                                                   \
        const int x_ = (X) & 15;                                               \
        const int a0_ = (((x_) * 64 + lane) * 8) ^ (x_ << 3);                  \
        const int a1_ = (((16 + x_) * 64 + lane) * 8) ^ (x_ << 3);             \
        AH[0] = *(const half8f*)&AhL[a0_];  AL[0] = *(const half8f*)&AlL[a0_]; \
        AH[1] = *(const half8f*)&AhL[a1_];  AL[1] = *(const half8f*)&AlL[a1_]; \
    } while (0)

    // 12 MFMAs, term-outer (dependent same-acc MFMAs 4 issues apart)
#define MFMA_BURST(AH, AL, BH, BL) do {                                                          \
        __builtin_amdgcn_s_setprio(1);                                                           \
        acc[0][0] = __builtin_amdgcn_mfma_f32_32x32x16_f16(AL[0], BH[0], acc[0][0], 0, 0, 0);    \
        acc[1][0] = __builtin_amdgcn_mfma_f32_32x32x16_f16(AL[1], BH[0], acc[1][0], 0, 0, 0);    \
        acc[0][1] = __builtin_amdgcn_mfma_f32_32x32x16_f16(AL[0], BH[1], acc[0][1], 0, 0, 0);    \
        acc[1][1] = __builtin_amdgcn_mfma_f32_32x32x16_f16(AL[1], BH[1], acc[1][1], 0, 0, 0);    \
        acc[0][0] = __builtin_amdgcn_mfma_f32_32x32x16_f16(AH[0], BL[0], acc[0][0], 0, 0, 0);    \
        acc[1][0] = __builtin_amdgcn_mfma_f32_32x32x16_f16(AH[1], BL[0], acc[1][0], 0, 0, 0);    \
        acc[0][1] = __builtin_amdgcn_mfma_f32_32x32x16_f16(AH[0], BL[1], acc[0][1], 0, 0, 0);    \
        acc[1][1] = __builtin_amdgcn_mfma_f32_32x32x16_f16(AH[1], BL[1], acc[1][1], 0, 0, 0);    \
        acc[0][0] = __builtin_amdgcn_mfma_f32_32x32x16_f16(AH[0], BH[0], acc[0][0], 0, 0, 0);    \
        acc[1][0] = __builtin_amdgcn_mfma_f32_32x32x16_f16(AH[1], BH[0], acc[1][0], 0, 0, 0);    \
        acc[0][1] = __builtin_amdgcn_mfma_f32_32x32x16_f16(AH[0], BH[1], acc[0][1], 0, 0, 0);    \
        acc[1][1] = __builtin_amdgcn_mfma_f32_32x32x16_f16(AH[1], BH[1], acc[1][1], 0, 0, 0);    \
        __builtin_amdgcn_s_setprio(0);                                                           \
    } while (0)

    half8f bh0[2], bl0[2], bh1[2], bl1[2], bh2[2], bl2[2], bh3[2], bl3[2];
    half8f ah0[2], al0[2], ah1[2], al1[2];

    size_t cb = ((size_t)(k0 >> 5) + wn * 2) * 512;   // c0i=0 tile base

    // prime the pipeline once (refilled across c0i by the X>=16 prefetches)
    PF_B(bh0, bl0, 0);
    PF_B(bh1, bl1, 1);
    PF_A(ah0, al0, 0);

    #pragma unroll 1
    for (int c0i = 0; c0i < KSLICE / 256; ++c0i) {   // 8 c0 tiles of 256 codes
        const int c0 = k0 + c0i * 256;

        // early hv2 prefetch (consumed only in the epilogue)
        const float hvv0 = hv2[c0 + (wn * 2 + 0) * 32 + (lane & 31)];
        const float hvv1 = hv2[c0 + (wn * 2 + 1) * 32 + (lane & 31)];

        floatx16 acc[2][2];
        #pragma unroll
        for (int mi = 0; mi < 2; ++mi)
            #pragma unroll
            for (int nj = 0; nj < 2; ++nj)
                #pragma unroll
                for (int r = 0; r < 16; ++r) acc[mi][nj][r] = 0.0f;

        #pragma unroll 1   // REAL loop: bounded hoist window (anti-spill)
        for (int g = 0; g < 4; ++g) {
            const int kt = g * 4;
            PF_B(bh2, bl2, kt + 2);  PF_A(ah1, al1, kt + 1);
            MFMA_BURST(ah0, al0, bh0, bl0);
            PF_B(bh3, bl3, kt + 3);  PF_A(ah0, al0, kt + 2);
            MFMA_BURST(ah1, al1, bh1, bl1);
            PF_B(bh0, bl0, kt + 4);  PF_A(ah1, al1, kt + 3);
            MFMA_BURST(ah0, al0, bh2, bl2);
            PF_B(bh1, bl1, kt + 5);  PF_A(ah0, al0, kt + 4);
            MFMA_BURST(ah1, al1, bh3, bl3);
        }
        // g=3 issued: B <- next tile slabs 0/1 (X=16,17), A <- slab 0. Pipeline stays hot.
        cb += 4096;

        // epilogue: s = 0.5*|v|^2 - dot; running first-argmin (ascending c per lane).
        // C/D layout (32x32, HW-measured): col = lane&31, row = (r&3)+8*(r>>2)+4*(lane>>5)
        #pragma unroll
        for (int nj = 0; nj < 2; ++nj) {
            const float hv = nj ? hvv1 : hvv0;
            const int c = c0 + (wn * 2 + nj) * 32 + (lane & 31);
            const unsigned clo = (unsigned)c;
            const unsigned chi = (unsigned)c << 16;
            #pragma unroll
            for (int mi = 0; mi < 2; ++mi)
                #pragma unroll
                for (int r = 0; r < 16; r += 2) {
                    const int b = mi * 16 + r;
                    float s0 = hv - acc[mi][nj][r];
                    float s1 = hv - acc[mi][nj][r + 1];
                    unsigned w = bidxp[b >> 1];
                    if (s0 < best[b])     { best[b] = s0;     w = (w & 0xFFFF0000u) | clo; }
                    if (s1 < best[b + 1]) { best[b + 1] = s1; w = (w & 0x0000FFFFu) | chi; }
                    bidxp[b >> 1] = w;
                }
        }
    }

    // unpack indices (registers are cheap after the hot loop)
    int bidx[32];
    #pragma unroll
    for (int b = 0; b < 32; ++b)
        bidx[b] = (b & 1) ? (int)(bidxp[b >> 1] >> 16) : (int)(bidxp[b >> 1] & 0xFFFFu);

    // reduce across the 32 col-lanes (same rows within each lane-half; xor<32 keeps lane>>5)
    #pragma unroll
    for (int off = 1; off < 32; off <<= 1) {
        #pragma unroll
        for (int b = 0; b < 32; ++b) {
            float ob = __shfl_xor(best[b], off, 64);
            int   oi = __shfl_xor(bidx[b], off, 64);
            if (ob < best[b] || (ob == best[b] && oi < bidx[b])) {
                best[b] = ob; bidx[b] = oi;
            }
        }
    }
    if ((lane & 31) == 0) {
        const size_t sl = (size_t)(slice * 4 + wn) * T_TOTAL;  // disjoint per (slice, wn)
        const int rowadd = (lane >> 5) * 4;
        #pragma unroll
        for (int mi = 0; mi < 2; ++mi)
            #pragma unroll
            for (int r = 0; r < 16; ++r) {
                int qr = q0 + mi * 32 + (r & 3) + 8 * (r >> 2) + rowadd;
                partial[sl + qr] = make_float2(best[mi * 16 + r], (float)bidx[mi * 16 + r]);
            }
    }
#undef PF_B
#undef PF_A
#undef MFMA_BURST
}

// ---- kernel 3a (fused, needs partial in ws): fold 16 slices + gather, wave per row ----
__global__ void redgather_kernel(const float* __restrict__ vocab,
                                 const float2* __restrict__ partial,
                                 float* __restrict__ out) {
    int r    = blockIdx.x * 4 + (threadIdx.x >> 6);
    int lane = threadIdx.x & 63;
    float bm = 3.4e38f;
    int   bi = 0x7fffffff;
    if (lane < 16) {
        float2 p = partial[(size_t)lane * T_TOTAL + r];
        bm = p.x; bi = (int)p.y;
    }
    #pragma unroll
    for (int off = 1; off < 16; off <<= 1) {   // xor<16 stays within the 16-lane group
        float ob = __shfl_xor(bm, off, 64);
        int   oi = __shfl_xor(bi, off, 64);
        if (ob < bm || (ob == bm && oi < bi)) { bm = ob; bi = oi; }
    }
    int k = __shfl(bi, 0, 64);                 // lanes 0-15 hold the true min; take lane 0
    const float4* src = (const float4*)(vocab + (size_t)k * D);
    float4*       dst = (float4*)(out + (size_t)r * D);
    dst[lane] = src[lane];
    if (lane == 0) out[(size_t)T_TOTAL * D + r] = (float)k;
}

// ---- kernel 3b/4b (fallback path, partial at d_out head): separate reduce + gather ----
__global__ void reduce_kernel(const float2* __restrict__ partial, int* __restrict__ idx) {
    int q = blockIdx.x * 256 + threadIdx.x;
    float bm = 3.4e38f;
    int   bi = 0x7fffffff;
    #pragma unroll
    for (int s = 0; s < NSLICE; ++s) {
        float2 p = partial[(size_t)s * T_TOTAL + q];
        int pi = (int)p.y;
        if (p.x < bm || (p.x == bm && pi < bi)) { bm = p.x; bi = pi; }
    }
    idx[q] = bi;
}

__global__ void gather_kernel(const float* __restrict__ vocab,
                              const int* __restrict__ idx,
                              float* __restrict__ out) {
    int r    = blockIdx.x * 4 + (threadIdx.x >> 6);
    int lane = threadIdx.x & 63;
    int k = idx[r];
    const float4* src = (const float4*)(vocab + (size_t)k * D);
    float4*       dst = (float4*)(out + (size_t)r * D);
    dst[lane] = src[lane];
    if (lane == 0) out[(size_t)T_TOTAL * D + r] = (float)k;
}

extern "C" void kernel_launch(void* const* d_in, const int* in_sizes, int n_in,
                              void* d_out, int out_size, void* d_ws, size_t ws_size,
                              hipStream_t stream) {
    const float* seq   = (const float*)d_in[0];   // [T, D] f32
    const float* vocab = (const float*)d_in[1];   // [K, D] f32
    float* out = (float*)d_out;

    float* hv2 = (float*)d_ws;                               // K floats
    _Float16* bhi = (_Float16*)(out + PARTIAL_F);            // 4 MB (d_out scratch)
    _Float16* blo = bhi + BHALVES;                           // 4 MB

    // partial placement: ws if it fits (enables fused reduce+gather — no cross-kernel
    // race since gather never writes ws), else d_out head (R12 2-kernel path).
    const size_t need_ws = (size_t)(K + 2 * NSLICE * T_TOTAL) * sizeof(float) + 256;
    const bool fused = ws_size >= need_ws;

    hipLaunchKernelGGL(prep_kernel, dim3(NCT32), dim3(256), 0, stream, vocab, bhi, blo, hv2);

    if (fused) {
        float2* partial = (float2*)(hv2 + K);                // in ws
        hipLaunchKernelGGL(argmin_kernel,    dim3(NQB * KSPLIT), dim3(256), 0, stream,
                           seq, bhi, blo, hv2, partial);
        hipLaunchKernelGGL(redgather_kernel, dim3(T_TOTAL / 4),  dim3(256), 0, stream,
                           vocab, partial, out);
    } else {
        float2* partial = (float2*)d_out;                    // at d_out head
        int* idx = (int*)(hv2 + K);                          // T ints in ws
        hipLaunchKernelGGL(argmin_kernel, dim3(NQB * KSPLIT), dim3(256), 0, stream,
                           seq, bhi, blo, hv2, partial);
        hipLaunchKernelGGL(reduce_kernel, dim3(T_TOTAL / 256), dim3(256), 0, stream, partial, idx);
        hipLaunchKernelGGL(gather_kernel, dim3(T_TOTAL / 4),   dim3(256), 0, stream, vocab, idx, out);
    }
}

// Round 3
// 434.064 us; speedup vs baseline: 1.1388x; 1.1388x over previous
//
#include <hip/hip_runtime.h>

// Problem constants: N=512, BS=64, DIM=256, SIZE=8192
#define T_TOTAL 32768   // N*BS queries
#define D       256
#define K       8192
#define BQ      64      // queries per block tile (4 row-tiles of 16) — shared by all 4 waves
#define KSPLIT  4
#define KSLICE  (K / KSPLIT)
#define NSLICE  (KSPLIT * 4)        // (slice, wn) pairs write disjoint partial slices
#define NCT     (K / 16)            // 512 code-tiles
#define KT_STRIDE (NCT * 64 * 8)    // halves per kt plane = 262144
#define NQB     (T_TOTAL / BQ)      // 512 query-blocks

typedef _Float16 half4f  __attribute__((ext_vector_type(4)));
typedef _Float16 half8f  __attribute__((ext_vector_type(8)));
typedef float    floatx4 __attribute__((ext_vector_type(4)));

// d_out scratch: Bhi/Blo after the first PARTIAL_F floats. If ws is big enough,
// partial lives in ws (enables fused reduce+gather); else at d_out head (R12 path).
#define PARTIAL_F 1048576
#define BHALVES   2097152   // halves per B array (8*512*64*8)

__device__ __forceinline__ _Float16 hi16(float x) { return (_Float16)x; }
__device__ __forceinline__ _Float16 lo16(float x, _Float16 h) { return (_Float16)(x - (float)h); }
__device__ __forceinline__ void split4(float4 v, half4f& h, half4f& l) {
    _Float16 hx = hi16(v.x), hy = hi16(v.y), hz = hi16(v.z), hw = hi16(v.w);
    h = (half4f){hx, hy, hz, hw};
    l = (half4f){lo16(v.x, hx), lo16(v.y, hy), lo16(v.z, hz), lo16(v.w, hw)};
}

// ---- kernel 1: fused vocab prep: hv2 (fp32-exact) + fp16 hi/lo fragment-order split ----
// 512 blocks, one 16-code tile each. Wave w handles codes 4w..4w+3 (lane = k4 along D).
__global__ void prep_kernel(const float* __restrict__ vocab,
                            _Float16* __restrict__ bhi, _Float16* __restrict__ blo,
                            float* __restrict__ hv2) {
    const int ct = blockIdx.x;
    const int t  = threadIdx.x;
    const int k4 = t & 63;               // float4 index along D
    const int w  = t >> 6;
    const float4* voc4 = (const float4*)vocab;
    const int kt = k4 >> 3, kg = (k4 >> 1) & 3, h = k4 & 1;
    float ss[4];
    #pragma unroll
    for (int ci = 0; ci < 4; ++ci) {
        int cc = w * 4 + ci;             // code within tile
        float4 v = voc4[(size_t)(ct * 16 + cc) * (D / 4) + k4];
        half4f hh, ll;
        split4(v, hh, ll);
        size_t off = (((size_t)kt * NCT + ct) * 64 + (cc + 16 * kg)) * 8 + h * 4;
        *(half4f*)&bhi[off] = hh;
        *(half4f*)&blo[off] = ll;
        ss[ci] = v.x * v.x + v.y * v.y + v.z * v.z + v.w * v.w;
    }
    #pragma unroll
    for (int ci = 0; ci < 4; ++ci) {
        float s = ss[ci];
        #pragma unroll
        for (int off = 32; off; off >>= 1) s += __shfl_down(s, off, 64);
        if ((t & 63) == 0) hv2[ct * 16 + w * 4 + ci] = 0.5f * s;
    }
}

// -------- kernel 2: MFMA argmin; 3-term split; depth-1 pipeline on BOTH A and B --------
// block 256 = 4 waves; wave wn 0..3 covers a code quadrant; all waves share 64 A rows.
// grid 2048 flattened; XCD swizzle locks one K-slice per XCD (B slice 2 MB < 4 MB L2).
// kt2 loop rolled (unroll 1): bounded hoist window (R8/R9 anti-spill lesson).
// Ping-pong on B (global, R12-proven) AND on A (LDS) to hide both latencies (R12 lesson).
// R3: parity s_sleep after the barrier de-phase-locks the 2 co-resident blocks so one
// block's VALU phases (epilogue/prologue) overlap the partner wave's MFMA bursts.
__launch_bounds__(256, 2)
__global__ void argmin_kernel(const float* __restrict__ seq,
                              const _Float16* __restrict__ bhi,
                              const _Float16* __restrict__ blo,
                              const float* __restrict__ hv2,
                              float2* __restrict__ partial) {
    // A LDS in fragment order [rt 0..3][kt 0..7][flane 0..63][8], XOR-swizzled by kt<<3
    __shared__ _Float16 AhL[4 * 8 * 64 * 8];   // 32 KB
    __shared__ _Float16 AlL[4 * 8 * 64 * 8];   // 32 KB

    const int t    = threadIdx.x;
    const int lane = t & 63;
    const int wn   = t >> 6;            // code quadrant 0..3
    const int bi   = blockIdx.x;
    const int slice = (bi & 7) >> 1;    // 0..3  (XCD-locked K-slice)
    const int qb    = (bi >> 3) * 2 + (bi & 1);  // 0..511
    const int q0   = qb * BQ;
    const int k0   = slice * KSLICE;

    const float4* seq4 = (const float4*)seq;

    // ---- prologue: split A (64 rows x 256 dims) into fragment-order LDS, once ----
    #pragma unroll
    for (int i = 0; i < 16; ++i) {
        int f   = t + 256 * i;          // 0..4095 float4s
        int row = f >> 6;               // 0..63
        int d4  = f & 63;               // float4 along D
        float4 v = seq4[(size_t)(q0 + row) * (D / 4) + d4];
        half4f h, l;
        split4(v, h, l);
        int kt = d4 >> 3, kg = (d4 >> 1) & 3, hh = d4 & 1;
        int off = (((((row >> 4) * 8 + kt) * 64) + ((row & 15) + 16 * kg)) * 8 + hh * 4)
                  ^ (kt << 3);          // swizzle: write conflicts 32-way -> 4-way
        *(half4f*)&AhL[off] = h;
        *(half4f*)&AlL[off] = l;
    }
    __syncthreads();   // the ONLY barrier

    // Phase-stagger: (bi ^ (bi>>8)) & 1 differs within the pair under both plausible
    // co-residency mappings ({2i,2i+1} and {i,i+256}). ~1280 idle cyc ≈ half a tile
    // period anti-aligns this block's MFMA bursts with its CU partner's VALU phases.
    // Worst case if theory is wrong: ~+0.5 µs per block slot.
    if ((bi ^ (bi >> 8)) & 1) {
        #pragma unroll
        for (int s_ = 0; s_ < 10; ++s_) __builtin_amdgcn_s_sleep(2);
    }

    float best[16];
    int   bidx[16];
    #pragma unroll
    for (int b = 0; b < 16; ++b) { best[b] = 3.4e38f; bidx[b] = 0; }

    const _Float16* bh_l = bhi + (size_t)lane * 8;
    const _Float16* bl_l = blo + (size_t)lane * 8;

    for (int c0i = 0; c0i < KSLICE / 256; ++c0i) {   // 8 c0 tiles of 256 codes
        const int c0  = k0 + c0i * 256;
        const int ct0 = (c0 >> 4) + wn * 4;          // this wave's 4 code-tiles
        const size_t cb = (size_t)ct0 * 512;

        floatx4 acc[4][4];
        #pragma unroll
        for (int mi = 0; mi < 4; ++mi)
            #pragma unroll
            for (int nj = 0; nj < 4; ++nj) acc[mi][nj] = (floatx4){0.f, 0.f, 0.f, 0.f};

        // ping-pong buffers: B (global) and A (LDS)
        half8f bh0[4], bl0[4], bh1[4], bl1[4];
        half8f ah0[4], al0[4], ah1[4], al1[4];
        #pragma unroll
        for (int nj = 0; nj < 4; ++nj) {          // preload kt=0
            bh0[nj] = *(const half8f*)&bh_l[cb + nj * 512];
            bl0[nj] = *(const half8f*)&bl_l[cb + nj * 512];
        }
        #pragma unroll
        for (int mi = 0; mi < 4; ++mi) {
            const int ao = ((mi * 8) * 64 + lane) * 8;   // kt=0: swizzle term is 0
            ah0[mi] = *(const half8f*)&AhL[ao];
            al0[mi] = *(const half8f*)&AlL[ao];
        }

        #pragma unroll 1   // REAL loop: bounded hoist window (anti-spill)
        for (int kt2 = 0; kt2 < 4; ++kt2) {
            const int kt = kt2 * 2;
            // prefetch kt+1: B -> buf1, A -> areg1 (both overlap kt's MFMA burst)
            {
                const size_t kb = (size_t)(kt + 1) * KT_STRIDE + cb;
                #pragma unroll
                for (int nj = 0; nj < 4; ++nj) {
                    bh1[nj] = *(const half8f*)&bh_l[kb + nj * 512];
                    bl1[nj] = *(const half8f*)&bl_l[kb + nj * 512];
                }
                #pragma unroll
                for (int mi = 0; mi < 4; ++mi) {
                    const int ao = (((mi * 8 + kt + 1) * 64 + lane) * 8) ^ ((kt + 1) << 3);
                    ah1[mi] = *(const half8f*)&AhL[ao];
                    al1[mi] = *(const half8f*)&AlL[ao];
                }
            }
            // MFMA kt with areg0/buf0 (3-term Markidis: ll dropped, err ~2e-6 << gaps)
            #pragma unroll
            for (int nj = 0; nj < 4; ++nj)
                #pragma unroll
                for (int mi = 0; mi < 4; ++mi) {
                    floatx4 a = acc[mi][nj];
                    a = __builtin_amdgcn_mfma_f32_16x16x32_f16(al0[mi], bh0[nj], a, 0, 0, 0);
                    a = __builtin_amdgcn_mfma_f32_16x16x32_f16(ah0[mi], bl0[nj], a, 0, 0, 0);
                    a = __builtin_amdgcn_mfma_f32_16x16x32_f16(ah0[mi], bh0[nj], a, 0, 0, 0);
                    acc[mi][nj] = a;
                }
            // prefetch kt+2 into buf0/areg0 (uniform branch; skipped on last lap)
            if (kt2 < 3) {
                const size_t kb = (size_t)(kt + 2) * KT_STRIDE + cb;
                #pragma unroll
                for (int nj = 0; nj < 4; ++nj) {
                    bh0[nj] = *(const half8f*)&bh_l[kb + nj * 512];
                    bl0[nj] = *(const half8f*)&bl_l[kb + nj * 512];
                }
                #pragma unroll
                for (int mi = 0; mi < 4; ++mi) {
                    const int ao = (((mi * 8 + kt + 2) * 64 + lane) * 8) ^ ((kt + 2) << 3);
                    ah0[mi] = *(const half8f*)&AhL[ao];
                    al0[mi] = *(const half8f*)&AlL[ao];
                }
            }
            // MFMA kt+1 with areg1/buf1
            #pragma unroll
            for (int nj = 0; nj < 4; ++nj)
                #pragma unroll
                for (int mi = 0; mi < 4; ++mi) {
                    floatx4 a = acc[mi][nj];
                    a = __builtin_amdgcn_mfma_f32_16x16x32_f16(al1[mi], bh1[nj], a, 0, 0, 0);
                    a = __builtin_amdgcn_mfma_f32_16x16x32_f16(ah1[mi], bl1[nj], a, 0, 0, 0);
                    a = __builtin_amdgcn_mfma_f32_16x16x32_f16(ah1[mi], bh1[nj], a, 0, 0, 0);
                    acc[mi][nj] = a;
                }
        }

        // epilogue: s = 0.5*|v|^2 - dot; running first-argmin (ascending c per lane).
        // C/D layout: col = lane&15, row = (lane>>4)*4 + reg
        #pragma unroll
        for (int nj = 0; nj < 4; ++nj) {
            int c = c0 + (wn * 4 + nj) * 16 + (lane & 15);
            float hv = hv2[c];
            #pragma unroll
            for (int mi = 0; mi < 4; ++mi)
                #pragma unroll
                for (int r = 0; r < 4; ++r) {
                    float s = hv - acc[mi][nj][r];
                    int b = mi * 4 + r;
                    if (s < best[b]) { best[b] = s; bidx[b] = c; }
                }
        }
    }

    // reduce across the 16 col-lanes (same rows, 16 different cols)
    #pragma unroll
    for (int off = 1; off < 16; off <<= 1) {
        #pragma unroll
        for (int b = 0; b < 16; ++b) {
            float ob = __shfl_xor(best[b], off, 64);
            int   oi = __shfl_xor(bidx[b], off, 64);
            if (ob < best[b] || (ob == best[b] && oi < bidx[b])) {
                best[b] = ob; bidx[b] = oi;
            }
        }
    }
    if ((lane & 15) == 0) {
        const size_t sl = (size_t)(slice * 4 + wn) * T_TOTAL;  // disjoint per (slice, wn)
        #pragma unroll
        for (int mi = 0; mi < 4; ++mi)
            #pragma unroll
            for (int r = 0; r < 4; ++r) {
                int q = q0 + mi * 16 + (lane >> 4) * 4 + r;
                partial[sl + q] = make_float2(best[mi * 4 + r], (float)bidx[mi * 4 + r]);
            }
    }
}

// ---- kernel 3a (fused, needs partial in ws): fold 16 slices + gather, wave per row ----
__global__ void redgather_kernel(const float* __restrict__ vocab,
                                 const float2* __restrict__ partial,
                                 float* __restrict__ out) {
    int r    = blockIdx.x * 4 + (threadIdx.x >> 6);
    int lane = threadIdx.x & 63;
    float bm = 3.4e38f;
    int   bi = 0x7fffffff;
    if (lane < 16) {
        float2 p = partial[(size_t)lane * T_TOTAL + r];
        bm = p.x; bi = (int)p.y;
    }
    #pragma unroll
    for (int off = 1; off < 16; off <<= 1) {   // xor<16 stays within the 16-lane group
        float ob = __shfl_xor(bm, off, 64);
        int   oi = __shfl_xor(bi, off, 64);
        if (ob < bm || (ob == bm && oi < bi)) { bm = ob; bi = oi; }
    }
    int k = __shfl(bi, 0, 64);                 // lanes 0-15 hold the true min; take lane 0
    const float4* src = (const float4*)(vocab + (size_t)k * D);
    float4*       dst = (float4*)(out + (size_t)r * D);
    dst[lane] = src[lane];
    if (lane == 0) out[(size_t)T_TOTAL * D + r] = (float)k;
}

// ---- kernel 3b/4b (fallback path, partial at d_out head): separate reduce + gather ----
__global__ void reduce_kernel(const float2* __restrict__ partial, int* __restrict__ idx) {
    int q = blockIdx.x * 256 + threadIdx.x;
    float bm = 3.4e38f;
    int   bi = 0x7fffffff;
    #pragma unroll
    for (int s = 0; s < NSLICE; ++s) {
        float2 p = partial[(size_t)s * T_TOTAL + q];
        int pi = (int)p.y;
        if (p.x < bm || (p.x == bm && pi < bi)) { bm = p.x; bi = pi; }
    }
    idx[q] = bi;
}

__global__ void gather_kernel(const float* __restrict__ vocab,
                              const int* __restrict__ idx,
                              float* __restrict__ out) {
    int r    = blockIdx.x * 4 + (threadIdx.x >> 6);
    int lane = threadIdx.x & 63;
    int k = idx[r];
    const float4* src = (const float4*)(vocab + (size_t)k * D);
    float4*       dst = (float4*)(out + (size_t)r * D);
    dst[lane] = src[lane];
    if (lane == 0) out[(size_t)T_TOTAL * D + r] = (float)k;
}

extern "C" void kernel_launch(void* const* d_in, const int* in_sizes, int n_in,
                              void* d_out, int out_size, void* d_ws, size_t ws_size,
                              hipStream_t stream) {
    const float* seq   = (const float*)d_in[0];   // [T, D] f32
    const float* vocab = (const float*)d_in[1];   // [K, D] f32
    float* out = (float*)d_out;

    float* hv2 = (float*)d_ws;                               // K floats
    _Float16* bhi = (_Float16*)(out + PARTIAL_F);            // 4 MB (d_out scratch)
    _Float16* blo = bhi + BHALVES;                           // 4 MB

    // partial placement: ws if it fits (enables fused reduce+gather — no cross-kernel
    // race since gather never writes ws), else d_out head (R12 2-kernel path).
    const size_t need_ws = (size_t)(K + 2 * NSLICE * T_TOTAL) * sizeof(float) + 256;
    const bool fused = ws_size >= need_ws;

    hipLaunchKernelGGL(prep_kernel, dim3(NCT), dim3(256), 0, stream, vocab, bhi, blo, hv2);

    if (fused) {
        float2* partial = (float2*)(hv2 + K);                // in ws
        hipLaunchKernelGGL(argmin_kernel,    dim3(NQB * KSPLIT), dim3(256), 0, stream,
                           seq, bhi, blo, hv2, partial);
        hipLaunchKernelGGL(redgather_kernel, dim3(T_TOTAL / 4),  dim3(256), 0, stream,
                           vocab, partial, out);
    } else {
        float2* partial = (float2*)d_out;                    // at d_out head
        int* idx = (int*)(hv2 + K);                          // T ints in ws
        hipLaunchKernelGGL(argmin_kernel, dim3(NQB * KSPLIT), dim3(256), 0, stream,
                           seq, bhi, blo, hv2, partial);
        hipLaunchKernelGGL(reduce_kernel, dim3(T_TOTAL / 256), dim3(256), 0, stream, partial, idx);
        hipLaunchKernelGGL(gather_kernel, dim3(T_TOTAL / 4),   dim3(256), 0, stream, vocab, idx, out);
    }
}